// Round 5
// baseline (282.604 us; speedup 1.0000x reference)
//
#include <hip/hip_runtime.h>
#include <math.h>

// Problem constants
#define B_  4
#define C_  256
#define N_  4096
#define CK_ 32
#define CV_ 128

typedef __attribute__((ext_vector_type(8))) short short8;   // 8 bf16 (x32 A/B frag)
typedef __attribute__((ext_vector_type(4))) short short4v;  // 4 bf16 (x16 A/B frag)
typedef __attribute__((ext_vector_type(4))) float f32x4;    // MFMA C/D frag
typedef unsigned short u16;
typedef unsigned int   u32;

static constexpr float LOG2E = 1.4426950408889634f;

static __device__ __forceinline__ u16 f2bf(float f) {       // fp32 -> bf16 RNE
    u32 u = __float_as_uint(f);
    u = (u + 0x7FFFu + ((u >> 16) & 1u)) >> 16;
    return (u16)u;
}
static __device__ __forceinline__ float bf2f(u16 h) {
    return __uint_as_float(((u32)h) << 16);
}
// fast pack of two positive floats to bf16x2 (round-half-up)
static __device__ __forceinline__ u32 pack2bf(float a, float b) {
    const u32 ua = (__float_as_uint(a) + 0x8000u) >> 16;
    const u32 ub = (__float_as_uint(b) + 0x8000u) & 0xFFFF0000u;
    return ua | ub;
}

// 16x16x16 bf16 MFMA. Device pass has the _1k builtin (verified: gfx950
// device compile succeeded in R4); the #else branch exists ONLY so the host
// compile pass parses — it is never executed on device.
static __device__ __forceinline__ f32x4 mfma16(short4v a, short4v b, f32x4 c) {
#if __has_builtin(__builtin_amdgcn_mfma_f32_16x16x16bf16_1k)
    return __builtin_amdgcn_mfma_f32_16x16x16bf16_1k(a, b, c, 0, 0, 0);
#else
    return c;   // host-pass stub
#endif
}

// ---------------------------------------------------------------------------
// Kernel 0a: weight convert. W16[192][256] = [theta*log2e; phi; g] bf16,
// ow16[256][128] bf16.
// ---------------------------------------------------------------------------
__global__ __launch_bounds__(256) void wconv_kernel(
    const float* __restrict__ theta_w, const float* __restrict__ phi_w,
    const float* __restrict__ g_w,     const float* __restrict__ o_w,
    u16* __restrict__ W16, u16* __restrict__ ow16)
{
    const int idx = blockIdx.x * 256 + threadIdx.x;
    if (idx < 8192)        W16[idx] = f2bf(theta_w[idx] * LOG2E);
    else if (idx < 16384)  W16[idx] = f2bf(phi_w[idx - 8192]);
    else if (idx < 49152)  W16[idx] = f2bf(g_w[idx - 16384]);
    else                   ow16[idx - 49152] = f2bf(o_w[idx - 49152]);
}

// ---------------------------------------------------------------------------
// Kernel 0b: x [B][C][N] fp32 -> xT16 [B][N][C] bf16 (transpose + convert).
// ---------------------------------------------------------------------------
__global__ __launch_bounds__(256) void xt_kernel(
    const float* __restrict__ x, u16* __restrict__ xT16)
{
    const int b = blockIdx.z, c0 = blockIdx.y * 64, n0 = blockIdx.x * 64;
    const int t = threadIdx.x;
    __shared__ float tile[64][65];

    const int cr = t >> 4, nc = (t & 15) * 4;
    #pragma unroll
    for (int it = 0; it < 4; ++it) {
        const float4 v = *(const float4*)(x + (size_t)(b * C_ + c0 + cr + it * 16) * N_ + n0 + nc);
        tile[cr + it * 16][nc + 0] = v.x; tile[cr + it * 16][nc + 1] = v.y;
        tile[cr + it * 16][nc + 2] = v.z; tile[cr + it * 16][nc + 3] = v.w;
    }
    __syncthreads();
    const int n = t >> 2, cg = (t & 3) * 16;
    union { u16 us[16]; uint4 u4[2]; } pk;
    #pragma unroll
    for (int e = 0; e < 16; ++e) pk.us[e] = f2bf(tile[cg + e][n]);
    uint4* dst = (uint4*)(xT16 + (size_t)(b * N_ + n0 + n) * C_ + c0 + cg);
    dst[0] = pk.u4[0]; dst[1] = pk.u4[1];
}

// ---------------------------------------------------------------------------
// Kernel 1: projections via MFMA, phase-split for parallelism.
// Grid (N/64, 3, B): y=0 -> theta/phi; y=1 -> g rows 0..63; y=2 -> g 64..127.
// ---------------------------------------------------------------------------
__global__ __launch_bounds__(256) void proj_mfma_kernel(
    const u16* __restrict__ xT16, const u16* __restrict__ W16,
    const float* __restrict__ theta_b, const float* __restrict__ phi_b,
    const float* __restrict__ g_b,
    u16* __restrict__ theta_t, u16* __restrict__ phi_t, u16* __restrict__ g16)
{
    const int b = blockIdx.z, n0 = blockIdx.x * 64, phase = blockIdx.y;
    const int w = threadIdx.x >> 6, lane = threadIdx.x & 63;
    const int lr = lane & 15, q = lane >> 4;
    const f32x4 zf = {0.f, 0.f, 0.f, 0.f};

    if (phase == 0) {
        // theta/phi: A = xT16 (m=pixel), B = W16 rows 0..63 -> D rows=n, cols=o
        const u16* xrow = xT16 + (size_t)(b * N_ + n0 + w * 16 + lr) * C_;
        f32x4 acc[4];
        #pragma unroll
        for (int nt = 0; nt < 4; ++nt) acc[nt] = zf;
        for (int ks = 0; ks < 8; ++ks) {
            const short8 aX = *(const short8*)(xrow + ks * 32 + q * 8);
            #pragma unroll
            for (int nt = 0; nt < 4; ++nt) {
                const short8 bW = *(const short8*)(W16 + (size_t)(nt * 16 + lr) * C_ + ks * 32 + q * 8);
                acc[nt] = __builtin_amdgcn_mfma_f32_16x16x32_bf16(aX, bW, acc[nt], 0, 0, 0);
            }
        }
        #pragma unroll
        for (int nt = 0; nt < 4; ++nt) {
            const int o = nt * 16 + lr;
            #pragma unroll
            for (int reg = 0; reg < 4; ++reg) {
                const int n = n0 + w * 16 + q * 4 + reg;
                if (nt < 2)
                    theta_t[(size_t)(b * N_ + n) * CK_ + o] = f2bf(acc[nt][reg] + theta_b[o] * LOG2E);
                else
                    phi_t[(size_t)(b * N_ + n) * CK_ + (o - 32)] = f2bf(acc[nt][reg] + phi_b[o - 32]);
            }
        }
    } else {
        // g: A = W16 row-block (m=c), B = xT16 (n=pixel) -> D rows=c
        const int crow = (phase - 1) * 64 + w * 16;
        f32x4 ag[4];
        #pragma unroll
        for (int nt = 0; nt < 4; ++nt) ag[nt] = zf;
        for (int ks = 0; ks < 8; ++ks) {
            const short8 aW = *(const short8*)(W16 + (size_t)(64 + crow + lr) * C_ + ks * 32 + q * 8);
            #pragma unroll
            for (int nt = 0; nt < 4; ++nt) {
                const short8 bX = *(const short8*)(xT16 + (size_t)(b * N_ + n0 + nt * 16 + lr) * C_ + ks * 32 + q * 8);
                ag[nt] = __builtin_amdgcn_mfma_f32_16x16x32_bf16(aW, bX, ag[nt], 0, 0, 0);
            }
        }
        #pragma unroll
        for (int nt = 0; nt < 4; ++nt) {
            #pragma unroll
            for (int reg = 0; reg < 4; ++reg) {
                const int c = crow + q * 4 + reg;
                const int n = n0 + nt * 16 + lr;
                g16[(size_t)(b * CV_ + c) * N_ + n] = f2bf(ag[nt][reg] + g_b[c]);
            }
        }
    }
}

// ---------------------------------------------------------------------------
// Kernel 2: Z[b][j] = sum_i exp2(S[i][j]) via MFMA.
// ---------------------------------------------------------------------------
__global__ __launch_bounds__(256) void colstats_kernel(
    const u16* __restrict__ theta_t, const u16* __restrict__ phi_t,
    float* __restrict__ Z)
{
    const int b  = blockIdx.z;
    const int j0 = blockIdx.x * 32;
    const int istart = blockIdx.y * (N_ / 4);
    const int tid = threadIdx.x;
    const int wave = tid >> 6, lane = tid & 63;
    const int lr = lane & 15, q = lane >> 4;

    const int jW = j0 + (wave & 1) * 16;
    const short8 bF = *(const short8*)(phi_t + (size_t)(b * N_ + jW + lr) * CK_ + q * 8);

    const u16* thp = theta_t + (size_t)b * N_ * CK_;
    const f32x4 zero = {0.f, 0.f, 0.f, 0.f};
    float zacc = 0.f;
    for (int it = istart + (wave >> 1) * 16; it < istart + N_ / 4; it += 32) {
        const short8 aF = *(const short8*)(thp + (size_t)(it + lr) * CK_ + q * 8);
        f32x4 S = __builtin_amdgcn_mfma_f32_16x16x32_bf16(aF, bF, zero, 0, 0, 0);
        zacc += exp2f(S[0]) + exp2f(S[1]) + exp2f(S[2]) + exp2f(S[3]);
    }
    zacc += __shfl_xor(zacc, 16);
    zacc += __shfl_xor(zacc, 32);
    if (lane < 16) atomicAdd(&Z[(size_t)b * N_ + jW + lr], zacc);
}

// ---------------------------------------------------------------------------
// Kernel 4: o_pre partial = sum_{j in quarter} g[c][j] * exp2(S[i][j]) / Z[j]
// REGISTER-ONLY E: S computed as D[m=j][n=i] (A=phi, B=theta) so each lane
// holds E(i=lane&15, j=quad*4+reg) == exactly the 16x16x16 A-frag layout.
// -> exp2 -> pack -> PV mfma16 from registers. No LDS in K-loop, no barriers,
// waves fully independent. Wave = 32 i x 128 c; grid (N/128, 4 j-quarters, B).
// Epilogue: per-wave LDS repack -> coalesced bf16 [n][cv] partial stores.
// ---------------------------------------------------------------------------
__global__ __launch_bounds__(256, 2) void opre_kernel(
    const u16* __restrict__ theta_t, const u16* __restrict__ phi_t,
    const u16* __restrict__ g16, const float* __restrict__ Z,
    u16* __restrict__ o_p)
{
    const int b = blockIdx.z, jh = blockIdx.y;
    const int w = threadIdx.x >> 6, lane = threadIdx.x & 63;
    const int lr = lane & 15, q = lane >> 4;
    const int i0 = blockIdx.x * 128 + w * 32;

    __shared__ u16 ep[4][32 * 136];   // per-wave epilogue repack (16B-aligned rows)

    // theta B-frags (n=i), invariant over j
    short8 thB[2];
    #pragma unroll
    for (int it = 0; it < 2; ++it)
        thB[it] = *(const short8*)(theta_t + (size_t)(b * N_ + i0 + it * 16 + lr) * CK_ + q * 8);

    f32x4 acc[2][8];
    #pragma unroll
    for (int it = 0; it < 2; ++it)
        #pragma unroll
        for (int ct = 0; ct < 8; ++ct) acc[it][ct] = (f32x4){0.f, 0.f, 0.f, 0.f};

    const f32x4 zf = {0.f, 0.f, 0.f, 0.f};
    const u16* pb = phi_t + (size_t)(b * N_) * CK_;
    const float* Zb = Z + (size_t)b * N_;
    const int jstart = jh * (N_ / 4);

    for (int j0 = jstart; j0 < jstart + N_ / 4; j0 += 64) {
        // phi A-frags + Z for this chunk
        short8 phA[4];
        float4 zv[4];
        #pragma unroll
        for (int jt = 0; jt < 4; ++jt) {
            phA[jt] = *(const short8*)(pb + (size_t)(j0 + jt * 16 + lr) * CK_ + q * 8);
            zv[jt]  = *(const float4*)(Zb + j0 + jt * 16 + q * 4);
        }

        // S -> E' -> packed A-frags for PV (all in registers)
        short4v a2[2][4];
        #pragma unroll
        for (int jt = 0; jt < 4; ++jt) {
            const float rz0 = __builtin_amdgcn_rcpf(zv[jt].x);
            const float rz1 = __builtin_amdgcn_rcpf(zv[jt].y);
            const float rz2 = __builtin_amdgcn_rcpf(zv[jt].z);
            const float rz3 = __builtin_amdgcn_rcpf(zv[jt].w);
            #pragma unroll
            for (int it = 0; it < 2; ++it) {
                const f32x4 S = __builtin_amdgcn_mfma_f32_16x16x32_bf16(phA[jt], thB[it], zf, 0, 0, 0);
                const float e0 = exp2f(S[0]) * rz0;
                const float e1 = exp2f(S[1]) * rz1;
                const float e2 = exp2f(S[2]) * rz2;
                const float e3 = exp2f(S[3]) * rz3;
                union { u32 u[2]; short4v s; } pk;
                pk.u[0] = pack2bf(e0, e1);
                pk.u[1] = pack2bf(e2, e3);
                a2[it][jt] = pk.s;
            }
        }

        // PV: acc[it][ct] += E(i,j) * g(c,j), B-frag = g from global (L1-hot)
        #pragma unroll
        for (int ct = 0; ct < 8; ++ct) {
            const u16* gp = g16 + (size_t)(b * CV_ + ct * 16 + lr) * N_ + j0 + q * 4;
            #pragma unroll
            for (int jt = 0; jt < 4; ++jt) {
                const short4v gB = *(const short4v*)(gp + jt * 16);
                acc[0][ct] = mfma16(a2[0][jt], gB, acc[0][ct]);
                acc[1][ct] = mfma16(a2[1][jt], gB, acc[1][ct]);
            }
        }
    }

    // epilogue: D[m=i][n=c]: lane holds (i = it*16+4q+reg, c = ct*16+lr).
    // Repack via per-wave LDS -> coalesced bf16 [n][cv] stores.
    u16* myep = ep[w];
    #pragma unroll
    for (int it = 0; it < 2; ++it)
        #pragma unroll
        for (int ct = 0; ct < 8; ++ct)
            #pragma unroll
            for (int reg = 0; reg < 4; ++reg)
                myep[(it * 16 + q * 4 + reg) * 136 + ct * 16 + lr] = f2bf(acc[it][ct][reg]);
    __builtin_amdgcn_s_waitcnt(0);   // own-wave LDS writes visible

    u16* op = o_p + ((size_t)(jh * B_ + b) * N_) * CV_;
    #pragma unroll
    for (int inst = 0; inst < 8; ++inst) {
        const int row = inst * 4 + q;
        const uint4 v = *(const uint4*)(myep + row * 136 + lr * 8);
        *(uint4*)(op + (size_t)(i0 + row) * CV_ + lr * 8) = v;
    }
}

// ---------------------------------------------------------------------------
// Kernel 5: out = x + gamma * (o_w @ sum_p o_p + o_b) via MFMA.
// Grid (N/64, 2 oc-halves, B), block 256. Wave: 2 oc m-tiles x 64 n.
// ---------------------------------------------------------------------------
__global__ __launch_bounds__(256) void final_mfma_kernel(
    const u16* __restrict__ o_p, const u16* __restrict__ ow16,
    const float* __restrict__ o_b, const float* __restrict__ gamma,
    const float* __restrict__ x, float* __restrict__ out)
{
    const int b = blockIdx.z, ych = blockIdx.y, n0 = blockIdx.x * 64;
    const int w = threadIdx.x >> 6, lane = threadIdx.x & 63;
    const int lr = lane & 15, q = lane >> 4;
    const size_t PSTRIDE = (size_t)B_ * N_ * CV_;

    f32x4 acc[2][4];
    #pragma unroll
    for (int mt = 0; mt < 2; ++mt)
        #pragma unroll
        for (int nt = 0; nt < 4; ++nt) acc[mt][nt] = (f32x4){0.f, 0.f, 0.f, 0.f};

    for (int ks = 0; ks < 4; ++ks) {
        short8 bP[4];
        #pragma unroll
        for (int nt = 0; nt < 4; ++nt) {
            const size_t pbase = (size_t)(b * N_ + n0 + nt * 16 + lr) * CV_ + ks * 32 + q * 8;
            float s[8] = {0.f, 0.f, 0.f, 0.f, 0.f, 0.f, 0.f, 0.f};
            #pragma unroll
            for (int part = 0; part < 4; ++part) {
                const uint4 raw = *(const uint4*)(o_p + part * PSTRIDE + pbase);
                const u16* pr = (const u16*)&raw;
                #pragma unroll
                for (int e = 0; e < 8; ++e) s[e] += bf2f(pr[e]);
            }
            union { u16 us[8]; short8 s8; } pk;
            #pragma unroll
            for (int e = 0; e < 8; ++e) pk.us[e] = f2bf(s[e]);
            bP[nt] = pk.s8;
        }
        #pragma unroll
        for (int mt = 0; mt < 2; ++mt) {
            const int ocb = ych * 128 + (w * 2 + mt) * 16;
            const short8 aW = *(const short8*)(ow16 + (size_t)(ocb + lr) * CV_ + ks * 32 + q * 8);
            #pragma unroll
            for (int nt = 0; nt < 4; ++nt)
                acc[mt][nt] = __builtin_amdgcn_mfma_f32_16x16x32_bf16(aW, bP[nt], acc[mt][nt], 0, 0, 0);
        }
    }

    const float gm = gamma[0];
    #pragma unroll
    for (int mt = 0; mt < 2; ++mt) {
        #pragma unroll
        for (int nt = 0; nt < 4; ++nt) {
            #pragma unroll
            for (int reg = 0; reg < 4; ++reg) {
                const int oc = ych * 128 + (w * 2 + mt) * 16 + q * 4 + reg;
                const int n = n0 + nt * 16 + lr;
                const size_t off = (size_t)(b * C_ + oc) * N_ + n;
                out[off] = x[off] + gm * (acc[mt][nt][reg] + o_b[oc]);
            }
        }
    }
}

// ---------------------------------------------------------------------------
extern "C" void kernel_launch(void* const* d_in, const int* in_sizes, int n_in,
                              void* d_out, int out_size, void* d_ws, size_t ws_size,
                              hipStream_t stream)
{
    const float* x       = (const float*)d_in[0];
    const float* theta_w = (const float*)d_in[1];
    const float* theta_b = (const float*)d_in[2];
    const float* phi_w   = (const float*)d_in[3];
    const float* phi_b   = (const float*)d_in[4];
    const float* g_w     = (const float*)d_in[5];
    const float* g_b     = (const float*)d_in[6];
    const float* o_w     = (const float*)d_in[7];
    const float* o_b     = (const float*)d_in[8];
    const float* gamma   = (const float*)d_in[9];
    float* out = (float*)d_out;

    // workspace: xT16 8MB | W16 96KB | ow16 64KB | theta_t 1MB | phi_t 1MB |
    //            g16 4MB | Z 64KB | o_p 4x4MB bf16 = 16MB    (~30.2 MB)
    u16* xT16    = (u16*)d_ws;
    u16* W16     = xT16 + (size_t)B_ * N_ * C_;
    u16* ow16    = W16 + 192 * C_;
    u16* theta_t = ow16 + C_ * CV_;
    u16* phi_t   = theta_t + (size_t)B_ * N_ * CK_;
    u16* g16     = phi_t + (size_t)B_ * N_ * CK_;
    float* Z     = (float*)(g16 + (size_t)B_ * CV_ * N_);
    u16* o_p     = (u16*)(Z + (size_t)B_ * N_);

    (void)hipMemsetAsync(Z, 0, (size_t)B_ * N_ * sizeof(float), stream);

    wconv_kernel<<<dim3(320), 256, 0, stream>>>(theta_w, phi_w, g_w, o_w, W16, ow16);
    xt_kernel<<<dim3(N_ / 64, C_ / 64, B_), 256, 0, stream>>>(x, xT16);
    proj_mfma_kernel<<<dim3(N_ / 64, 3, B_), 256, 0, stream>>>(
        xT16, W16, theta_b, phi_b, g_b, theta_t, phi_t, g16);
    colstats_kernel<<<dim3(N_ / 32, 4, B_), 256, 0, stream>>>(theta_t, phi_t, Z);
    opre_kernel<<<dim3(N_ / 128, 4, B_), 256, 0, stream>>>(theta_t, phi_t, g16, Z, o_p);
    final_mfma_kernel<<<dim3(N_ / 64, 2, B_), 256, 0, stream>>>(
        o_p, ow16, o_b, gamma, x, out);
}

// Round 6
// 249.482 us; speedup vs baseline: 1.1328x; 1.1328x over previous
//
#include <hip/hip_runtime.h>
#include <math.h>

// Problem constants
#define B_  4
#define C_  256
#define N_  4096
#define CK_ 32
#define CV_ 128

typedef __attribute__((ext_vector_type(8))) short short8;   // 8 bf16 (x32 A/B frag)
typedef __attribute__((ext_vector_type(4))) float f32x4;    // MFMA C/D frag
typedef unsigned short u16;
typedef unsigned int   u32;

static constexpr float LOG2E = 1.4426950408889634f;

static __device__ __forceinline__ u16 f2bf(float f) {       // fp32 -> bf16 RNE
    u32 u = __float_as_uint(f);
    u = (u + 0x7FFFu + ((u >> 16) & 1u)) >> 16;
    return (u16)u;
}
static __device__ __forceinline__ float bf2f(u16 h) {
    return __uint_as_float(((u32)h) << 16);
}
// fast pack of two positive floats to bf16x2 (round-half-up)
static __device__ __forceinline__ u32 pack2bf(float a, float b) {
    const u32 ua = (__float_as_uint(a) + 0x8000u) >> 16;
    const u32 ub = (__float_as_uint(b) + 0x8000u) & 0xFFFF0000u;
    return ua | ub;
}
// wait lgkmcnt(0) ONLY (vmcnt=63, expcnt=7 stay open): gfx9 encoding
// simm16 = vmcnt[3:0] | expcnt<<4 | lgkmcnt<<8 | vmcnt_hi<<14 = 0xC07F
static __device__ __forceinline__ void wait_lds() {
    __builtin_amdgcn_s_waitcnt(0xC07F);
}

// ---------------------------------------------------------------------------
// Kernel 0a: weight convert. W16[192][256] = [theta*log2e; phi; g] bf16,
// ow16[256][128] bf16.
// ---------------------------------------------------------------------------
__global__ __launch_bounds__(256) void wconv_kernel(
    const float* __restrict__ theta_w, const float* __restrict__ phi_w,
    const float* __restrict__ g_w,     const float* __restrict__ o_w,
    u16* __restrict__ W16, u16* __restrict__ ow16)
{
    const int idx = blockIdx.x * 256 + threadIdx.x;
    if (idx < 8192)        W16[idx] = f2bf(theta_w[idx] * LOG2E);
    else if (idx < 16384)  W16[idx] = f2bf(phi_w[idx - 8192]);
    else if (idx < 49152)  W16[idx] = f2bf(g_w[idx - 16384]);
    else                   ow16[idx - 49152] = f2bf(o_w[idx - 49152]);
}

// ---------------------------------------------------------------------------
// Kernel 0b: x [B][C][N] fp32 -> xT16 [B][N][C] bf16 (transpose + convert).
// ---------------------------------------------------------------------------
__global__ __launch_bounds__(256) void xt_kernel(
    const float* __restrict__ x, u16* __restrict__ xT16)
{
    const int b = blockIdx.z, c0 = blockIdx.y * 64, n0 = blockIdx.x * 64;
    const int t = threadIdx.x;
    __shared__ float tile[64][65];

    const int cr = t >> 4, nc = (t & 15) * 4;
    #pragma unroll
    for (int it = 0; it < 4; ++it) {
        const float4 v = *(const float4*)(x + (size_t)(b * C_ + c0 + cr + it * 16) * N_ + n0 + nc);
        tile[cr + it * 16][nc + 0] = v.x; tile[cr + it * 16][nc + 1] = v.y;
        tile[cr + it * 16][nc + 2] = v.z; tile[cr + it * 16][nc + 3] = v.w;
    }
    __syncthreads();
    const int n = t >> 2, cg = (t & 3) * 16;
    union { u16 us[16]; uint4 u4[2]; } pk;
    #pragma unroll
    for (int e = 0; e < 16; ++e) pk.us[e] = f2bf(tile[cg + e][n]);
    uint4* dst = (uint4*)(xT16 + (size_t)(b * N_ + n0 + n) * C_ + c0 + cg);
    dst[0] = pk.u4[0]; dst[1] = pk.u4[1];
}

// ---------------------------------------------------------------------------
// Kernel 1: projections via MFMA, phase-split for parallelism.
// Grid (N/64, 3, B): y=0 -> theta/phi; y=1 -> g rows 0..63; y=2 -> g 64..127.
// ---------------------------------------------------------------------------
__global__ __launch_bounds__(256) void proj_mfma_kernel(
    const u16* __restrict__ xT16, const u16* __restrict__ W16,
    const float* __restrict__ theta_b, const float* __restrict__ phi_b,
    const float* __restrict__ g_b,
    u16* __restrict__ theta_t, u16* __restrict__ phi_t, u16* __restrict__ g16)
{
    const int b = blockIdx.z, n0 = blockIdx.x * 64, phase = blockIdx.y;
    const int w = threadIdx.x >> 6, lane = threadIdx.x & 63;
    const int lr = lane & 15, q = lane >> 4;
    const f32x4 zf = {0.f, 0.f, 0.f, 0.f};

    if (phase == 0) {
        // theta/phi: A = xT16 (m=pixel), B = W16 rows 0..63 -> D rows=n, cols=o
        const u16* xrow = xT16 + (size_t)(b * N_ + n0 + w * 16 + lr) * C_;
        f32x4 acc[4];
        #pragma unroll
        for (int nt = 0; nt < 4; ++nt) acc[nt] = zf;
        for (int ks = 0; ks < 8; ++ks) {
            const short8 aX = *(const short8*)(xrow + ks * 32 + q * 8);
            #pragma unroll
            for (int nt = 0; nt < 4; ++nt) {
                const short8 bW = *(const short8*)(W16 + (size_t)(nt * 16 + lr) * C_ + ks * 32 + q * 8);
                acc[nt] = __builtin_amdgcn_mfma_f32_16x16x32_bf16(aX, bW, acc[nt], 0, 0, 0);
            }
        }
        #pragma unroll
        for (int nt = 0; nt < 4; ++nt) {
            const int o = nt * 16 + lr;
            #pragma unroll
            for (int reg = 0; reg < 4; ++reg) {
                const int n = n0 + w * 16 + q * 4 + reg;
                if (nt < 2)
                    theta_t[(size_t)(b * N_ + n) * CK_ + o] = f2bf(acc[nt][reg] + theta_b[o] * LOG2E);
                else
                    phi_t[(size_t)(b * N_ + n) * CK_ + (o - 32)] = f2bf(acc[nt][reg] + phi_b[o - 32]);
            }
        }
    } else {
        // g: A = W16 row-block (m=c), B = xT16 (n=pixel) -> D rows=c
        const int crow = (phase - 1) * 64 + w * 16;
        f32x4 ag[4];
        #pragma unroll
        for (int nt = 0; nt < 4; ++nt) ag[nt] = zf;
        for (int ks = 0; ks < 8; ++ks) {
            const short8 aW = *(const short8*)(W16 + (size_t)(64 + crow + lr) * C_ + ks * 32 + q * 8);
            #pragma unroll
            for (int nt = 0; nt < 4; ++nt) {
                const short8 bX = *(const short8*)(xT16 + (size_t)(b * N_ + n0 + nt * 16 + lr) * C_ + ks * 32 + q * 8);
                ag[nt] = __builtin_amdgcn_mfma_f32_16x16x32_bf16(aW, bX, ag[nt], 0, 0, 0);
            }
        }
        #pragma unroll
        for (int nt = 0; nt < 4; ++nt) {
            #pragma unroll
            for (int reg = 0; reg < 4; ++reg) {
                const int c = crow + q * 4 + reg;
                const int n = n0 + nt * 16 + lr;
                g16[(size_t)(b * CV_ + c) * N_ + n] = f2bf(ag[nt][reg] + g_b[c]);
            }
        }
    }
}

// ---------------------------------------------------------------------------
// Kernel 2: Z[b][j] = sum_i exp2(S[i][j]) via MFMA.
// ---------------------------------------------------------------------------
__global__ __launch_bounds__(256) void colstats_kernel(
    const u16* __restrict__ theta_t, const u16* __restrict__ phi_t,
    float* __restrict__ Z)
{
    const int b  = blockIdx.z;
    const int j0 = blockIdx.x * 32;
    const int istart = blockIdx.y * (N_ / 4);
    const int tid = threadIdx.x;
    const int wave = tid >> 6, lane = tid & 63;
    const int lr = lane & 15, q = lane >> 4;

    const int jW = j0 + (wave & 1) * 16;
    const short8 bF = *(const short8*)(phi_t + (size_t)(b * N_ + jW + lr) * CK_ + q * 8);

    const u16* thp = theta_t + (size_t)b * N_ * CK_;
    const f32x4 zero = {0.f, 0.f, 0.f, 0.f};
    float zacc = 0.f;
    for (int it = istart + (wave >> 1) * 16; it < istart + N_ / 4; it += 32) {
        const short8 aF = *(const short8*)(thp + (size_t)(it + lr) * CK_ + q * 8);
        f32x4 S = __builtin_amdgcn_mfma_f32_16x16x32_bf16(aF, bF, zero, 0, 0, 0);
        zacc += exp2f(S[0]) + exp2f(S[1]) + exp2f(S[2]) + exp2f(S[3]);
    }
    zacc += __shfl_xor(zacc, 16);
    zacc += __shfl_xor(zacc, 32);
    if (lane < 16) atomicAdd(&Z[(size_t)b * N_ + jW + lr], zacc);
}

// ---------------------------------------------------------------------------
// Kernel 4: o_pre partial = sum_{j in quarter} g[c][j] * exp2(S[i][j]) / Z[j]
// WAVE-PRIVATE LDS transpose, no barriers. Wave = 32-i strip x 128 c.
// S-phase: A=phi(m=j), B=theta(n=i) -> lane holds E(i=lr, j=4q+reg) -> 8B
// contiguous ds_write_b64 into own region -> ds_read_b128 as x32 B-frags.
// PV: A = g 16B frags (L2-hot, each reused for 2 i-tiles), 16x16x32 MFMA.
// E-read amplification = 1x (vs R3's 8x). Grid (N/128, 4 jq, B) = 512 blocks.
// ---------------------------------------------------------------------------
__global__ __launch_bounds__(256, 2) void opre_kernel(
    const u16* __restrict__ theta_t, const u16* __restrict__ phi_t,
    const u16* __restrict__ g16, const float* __restrict__ Z,
    u16* __restrict__ o_p)
{
    const int b = blockIdx.z, jh = blockIdx.y;
    const int w = threadIdx.x >> 6, lane = threadIdx.x & 63;
    const int lr = lane & 15, q = lane >> 4;
    const int iw = blockIdx.x * 128 + w * 32;         // wave's 32-i strip

    __shared__ u16 El[4][32 * 72];                    // wave-private, 18.4 KB
    u16* Ew = El[w];

    // theta B-frags (n=i), invariant over j
    short8 thB[2];
    #pragma unroll
    for (int it = 0; it < 2; ++it)
        thB[it] = *(const short8*)(theta_t + (size_t)(b * N_ + iw + it * 16 + lr) * CK_ + q * 8);

    f32x4 acc[2][8];                                  // [i-tile][c-tile]
    #pragma unroll
    for (int it = 0; it < 2; ++it)
        #pragma unroll
        for (int ct = 0; ct < 8; ++ct) acc[it][ct] = (f32x4){0.f, 0.f, 0.f, 0.f};

    const f32x4 zf = {0.f, 0.f, 0.f, 0.f};
    const u16* pb = phi_t + (size_t)(b * N_) * CK_;
    const float* Zb = Z + (size_t)b * N_;
    const u16* gbase = g16 + (size_t)(b * CV_) * N_;
    const int jstart = jh * (N_ / 4);

    for (int j0 = jstart; j0 < jstart + N_ / 4; j0 += 64) {
        // phi A-frags + Z for this 64-j chunk
        short8 phA[4];
        float4 zv[4];
        #pragma unroll
        for (int jt = 0; jt < 4; ++jt) {
            phA[jt] = *(const short8*)(pb + (size_t)(j0 + jt * 16 + lr) * CK_ + q * 8);
            zv[jt]  = *(const float4*)(Zb + j0 + jt * 16 + q * 4);
        }

        // S -> E -> wave-private LDS (8B contiguous per lane)
        #pragma unroll
        for (int jt = 0; jt < 4; ++jt) {
            const float rz0 = __builtin_amdgcn_rcpf(zv[jt].x);
            const float rz1 = __builtin_amdgcn_rcpf(zv[jt].y);
            const float rz2 = __builtin_amdgcn_rcpf(zv[jt].z);
            const float rz3 = __builtin_amdgcn_rcpf(zv[jt].w);
            #pragma unroll
            for (int it = 0; it < 2; ++it) {
                const f32x4 S = __builtin_amdgcn_mfma_f32_16x16x32_bf16(phA[jt], thB[it], zf, 0, 0, 0);
                uint2 ev;
                ev.x = pack2bf(exp2f(S[0]) * rz0, exp2f(S[1]) * rz1);
                ev.y = pack2bf(exp2f(S[2]) * rz2, exp2f(S[3]) * rz3);
                *(uint2*)(Ew + (it * 16 + lr) * 72 + jt * 16 + q * 4) = ev;
            }
        }
        wait_lds();   // own-wave writes done before reads (no barrier needed)

        // PV: acc[it][ct] += g(c,j) . E(i,j);  A = g (m=c), B = E (n=i)
        #pragma unroll
        for (int j32 = 0; j32 < 2; ++j32) {
            const short8 bE0 = *(const short8*)(Ew + lr * 72 + j32 * 32 + q * 8);
            const short8 bE1 = *(const short8*)(Ew + (16 + lr) * 72 + j32 * 32 + q * 8);
            #pragma unroll
            for (int ct = 0; ct < 8; ++ct) {
                const short8 gA = *(const short8*)(gbase + (size_t)(ct * 16 + lr) * N_ + j0 + j32 * 32 + q * 8);
                acc[0][ct] = __builtin_amdgcn_mfma_f32_16x16x32_bf16(gA, bE0, acc[0][ct], 0, 0, 0);
                acc[1][ct] = __builtin_amdgcn_mfma_f32_16x16x32_bf16(gA, bE1, acc[1][ct], 0, 0, 0);
            }
        }
    }

    // epilogue: lane holds (c = ct*16+4q+reg, i = iw+it*16+lr). Two passes
    // through the wave's LDS region -> coalesced bf16 [n][cv] stores.
    u16* op = o_p + (size_t)(jh * B_ + b) * N_ * CV_;
    #pragma unroll
    for (int p = 0; p < 2; ++p) {
        #pragma unroll
        for (int ct = 0; ct < 8; ++ct) {
            uint2 ev;
            ev.x = pack2bf(acc[p][ct][0] < 0 ? 0 : acc[p][ct][0], 0.f);   // placeholder, replaced below
            // direct pack (values may be negative -> use f2bf)
            union { u16 us[4]; uint2 u2; } pk;
            #pragma unroll
            for (int reg = 0; reg < 4; ++reg) pk.us[reg] = f2bf(acc[p][ct][reg]);
            *(uint2*)(Ew + lr * 136 + ct * 16 + q * 4) = pk.u2;
            (void)ev;
        }
        wait_lds();
        #pragma unroll
        for (int inst = 0; inst < 4; ++inst) {
            const int row = lane >> 2;                    // 0..15
            const int col = ((lane & 3) + inst * 4) * 8;  // u16 col
            const uint4 v = *(const uint4*)(Ew + row * 136 + col);
            *(uint4*)(op + (size_t)(iw + p * 16 + row) * CV_ + col) = v;
        }
        wait_lds();   // reads done before next pass overwrites
    }
}

// ---------------------------------------------------------------------------
// Kernel 5: out = x + gamma * (o_w @ sum_p o_p + o_b) via MFMA.
// Grid (N/64, 2 oc-halves, B), block 256. Wave: 2 oc m-tiles x 64 n.
// ---------------------------------------------------------------------------
__global__ __launch_bounds__(256) void final_mfma_kernel(
    const u16* __restrict__ o_p, const u16* __restrict__ ow16,
    const float* __restrict__ o_b, const float* __restrict__ gamma,
    const float* __restrict__ x, float* __restrict__ out)
{
    const int b = blockIdx.z, ych = blockIdx.y, n0 = blockIdx.x * 64;
    const int w = threadIdx.x >> 6, lane = threadIdx.x & 63;
    const int lr = lane & 15, q = lane >> 4;
    const size_t PSTRIDE = (size_t)B_ * N_ * CV_;

    f32x4 acc[2][4];
    #pragma unroll
    for (int mt = 0; mt < 2; ++mt)
        #pragma unroll
        for (int nt = 0; nt < 4; ++nt) acc[mt][nt] = (f32x4){0.f, 0.f, 0.f, 0.f};

    for (int ks = 0; ks < 4; ++ks) {
        short8 bP[4];
        #pragma unroll
        for (int nt = 0; nt < 4; ++nt) {
            const size_t pbase = (size_t)(b * N_ + n0 + nt * 16 + lr) * CV_ + ks * 32 + q * 8;
            float s[8] = {0.f, 0.f, 0.f, 0.f, 0.f, 0.f, 0.f, 0.f};
            #pragma unroll
            for (int part = 0; part < 4; ++part) {
                const uint4 raw = *(const uint4*)(o_p + part * PSTRIDE + pbase);
                const u16* pr = (const u16*)&raw;
                #pragma unroll
                for (int e = 0; e < 8; ++e) s[e] += bf2f(pr[e]);
            }
            union { u16 us[8]; short8 s8; } pk;
            #pragma unroll
            for (int e = 0; e < 8; ++e) pk.us[e] = f2bf(s[e]);
            bP[nt] = pk.s8;
        }
        #pragma unroll
        for (int mt = 0; mt < 2; ++mt) {
            const int ocb = ych * 128 + (w * 2 + mt) * 16;
            const short8 aW = *(const short8*)(ow16 + (size_t)(ocb + lr) * CV_ + ks * 32 + q * 8);
            #pragma unroll
            for (int nt = 0; nt < 4; ++nt)
                acc[mt][nt] = __builtin_amdgcn_mfma_f32_16x16x32_bf16(aW, bP[nt], acc[mt][nt], 0, 0, 0);
        }
    }

    const float gm = gamma[0];
    #pragma unroll
    for (int mt = 0; mt < 2; ++mt) {
        #pragma unroll
        for (int nt = 0; nt < 4; ++nt) {
            #pragma unroll
            for (int reg = 0; reg < 4; ++reg) {
                const int oc = ych * 128 + (w * 2 + mt) * 16 + q * 4 + reg;
                const int n = n0 + nt * 16 + lr;
                const size_t off = (size_t)(b * C_ + oc) * N_ + n;
                out[off] = x[off] + gm * (acc[mt][nt][reg] + o_b[oc]);
            }
        }
    }
}

// ---------------------------------------------------------------------------
extern "C" void kernel_launch(void* const* d_in, const int* in_sizes, int n_in,
                              void* d_out, int out_size, void* d_ws, size_t ws_size,
                              hipStream_t stream)
{
    const float* x       = (const float*)d_in[0];
    const float* theta_w = (const float*)d_in[1];
    const float* theta_b = (const float*)d_in[2];
    const float* phi_w   = (const float*)d_in[3];
    const float* phi_b   = (const float*)d_in[4];
    const float* g_w     = (const float*)d_in[5];
    const float* g_b     = (const float*)d_in[6];
    const float* o_w     = (const float*)d_in[7];
    const float* o_b     = (const float*)d_in[8];
    const float* gamma   = (const float*)d_in[9];
    float* out = (float*)d_out;

    // workspace: xT16 8MB | W16 96KB | ow16 64KB | theta_t 1MB | phi_t 1MB |
    //            g16 4MB | Z 64KB | o_p 4x4MB bf16 = 16MB    (~30.2 MB)
    u16* xT16    = (u16*)d_ws;
    u16* W16     = xT16 + (size_t)B_ * N_ * C_;
    u16* ow16    = W16 + 192 * C_;
    u16* theta_t = ow16 + C_ * CV_;
    u16* phi_t   = theta_t + (size_t)B_ * N_ * CK_;
    u16* g16     = phi_t + (size_t)B_ * N_ * CK_;
    float* Z     = (float*)(g16 + (size_t)B_ * CV_ * N_);
    u16* o_p     = (u16*)(Z + (size_t)B_ * N_);

    (void)hipMemsetAsync(Z, 0, (size_t)B_ * N_ * sizeof(float), stream);

    wconv_kernel<<<dim3(320), 256, 0, stream>>>(theta_w, phi_w, g_w, o_w, W16, ow16);
    xt_kernel<<<dim3(N_ / 64, C_ / 64, B_), 256, 0, stream>>>(x, xT16);
    proj_mfma_kernel<<<dim3(N_ / 64, 3, B_), 256, 0, stream>>>(
        xT16, W16, theta_b, phi_b, g_b, theta_t, phi_t, g16);
    colstats_kernel<<<dim3(N_ / 32, 4, B_), 256, 0, stream>>>(theta_t, phi_t, Z);
    opre_kernel<<<dim3(N_ / 128, 4, B_), 256, 0, stream>>>(theta_t, phi_t, g16, Z, o_p);
    final_mfma_kernel<<<dim3(N_ / 64, 2, B_), 256, 0, stream>>>(
        o_p, ow16, o_b, gamma, x, out);
}